// Round 1
// baseline (156.349 us; speedup 1.0000x reference)
//
#include <hip/hip_runtime.h>
#include <stdint.h>

typedef short bf16x8 __attribute__((ext_vector_type(8)));
typedef float f32x4 __attribute__((ext_vector_type(4)));

static __device__ __forceinline__ unsigned short f2bf(float f) {
  union { float f; uint32_t u; } c; c.f = f;
  uint32_t u = c.u;
  uint32_t r = (u + 0x7fffu + ((u >> 16) & 1u)) >> 16;  // RNE
  return (unsigned short)r;
}

__device__ __forceinline__ void gload_lds16(const void* g, void* l) {
  __builtin_amdgcn_global_load_lds((const __attribute__((address_space(1))) uint32_t*)g,
                                   (__attribute__((address_space(3))) uint32_t*)l, 16, 0, 0);
}

// ---------------------------------------------------------------------------
// Kernel 1: fp32 -> bf16 conversion of activations (q,k,v) and weights.
// Xb: [3][4096][1024] bf16, Wb: [3][1024][1024] bf16
// ---------------------------------------------------------------------------
__global__ __launch_bounds__(256) void k_convert(
    const float* __restrict__ q, const float* __restrict__ k, const float* __restrict__ v,
    const float* __restrict__ Wq, const float* __restrict__ Wk, const float* __restrict__ Wv,
    unsigned short* __restrict__ Xb, unsigned short* __restrict__ Wb) {
  const int NX4 = 3145728;  // 3*4194304/4
  const int NW4 = 786432;   // 3*1048576/4
  int i = blockIdx.x * 256 + threadIdx.x;
  if (i >= NX4 + NW4) return;
  const float* src; unsigned short* dst; int off4;
  if (i < NX4) {
    int a = i >> 20; off4 = i & 1048575;
    src = (a == 0) ? q : (a == 1) ? k : v;
    dst = Xb + (size_t)a * 4194304;
  } else {
    int j = i - NX4;
    int a = j >> 18; off4 = j & 262143;
    src = (a == 0) ? Wq : (a == 1) ? Wk : Wv;
    dst = Wb + (size_t)a * 1048576;
  }
  float4 f = ((const float4*)src)[off4];
  uint32_t lo = (uint32_t)f2bf(f.x) | ((uint32_t)f2bf(f.y) << 16);
  uint32_t hi = (uint32_t)f2bf(f.z) | ((uint32_t)f2bf(f.w) << 16);
  ((uint2*)dst)[off4] = make_uint2(lo, hi);
}

// ---------------------------------------------------------------------------
// Kernel 2: projection GEMMs  C[m,n] = X[m,:] . W[n,:] + bias[n]  (x W^T + b)
// grid (256, 3): 32x8 tiles of 128x128 per projection g.
// g==0 (Q): scale by 0.125/inv_scale, store Qh[b,h,s2,dh]
// g==1 (K): store Kh[b,h,s2,dh]
// g==2 (V): store VhT[b,h,dh,s2]  (transposed for attention PV)
// ---------------------------------------------------------------------------
__global__ __launch_bounds__(256) void k_proj(
    const unsigned short* __restrict__ Xb, const unsigned short* __restrict__ Wb,
    const float* __restrict__ bq, const float* __restrict__ bk, const float* __restrict__ bv,
    const float* __restrict__ inv_scale,
    unsigned short* __restrict__ Qh, unsigned short* __restrict__ Kh,
    unsigned short* __restrict__ VhT) {
  __shared__ __align__(16) unsigned short At[128 * 32];
  __shared__ __align__(16) unsigned short Bt[128 * 32];
  const int g = blockIdx.y;
  const int m0 = (blockIdx.x >> 3) * 128, n0 = (blockIdx.x & 7) * 128;
  const unsigned short* X = Xb + (size_t)g * 4194304;
  const unsigned short* W = Wb + (size_t)g * 1048576;
  const int tid = threadIdx.x;
  const int w = tid >> 6, lane = tid & 63;
  const int wr = w >> 1, wc = w & 1;
  const int lq = lane & 15, lg = lane >> 4;

  f32x4 acc[4][4];
#pragma unroll
  for (int a = 0; a < 4; a++)
#pragma unroll
    for (int b = 0; b < 4; b++) acc[a][b] = (f32x4){0.f, 0.f, 0.f, 0.f};

  for (int kt = 0; kt < 32; ++kt) {
#pragma unroll
    for (int p = 0; p < 2; ++p) {
      int i = (w * 2 + p) * 64 + lane;   // 0..511 chunk id, 4 chunks per row
      int row = i >> 2, c = i & 3;
      gload_lds16(X + (size_t)(m0 + row) * 1024 + kt * 32 + c * 8, (char*)At + i * 16);
      gload_lds16(W + (size_t)(n0 + row) * 1024 + kt * 32 + c * 8, (char*)Bt + i * 16);
    }
    __syncthreads();
    bf16x8 af[4], bfr[4];
#pragma unroll
    for (int mi = 0; mi < 4; mi++)
      af[mi] = *(const bf16x8*)((const char*)At + ((wr * 64 + mi * 16 + lq) * 64 + lg * 16));
#pragma unroll
    for (int ni = 0; ni < 4; ni++)
      bfr[ni] = *(const bf16x8*)((const char*)Bt + ((wc * 64 + ni * 16 + lq) * 64 + lg * 16));
#pragma unroll
    for (int mi = 0; mi < 4; mi++)
#pragma unroll
      for (int ni = 0; ni < 4; ni++)
        acc[mi][ni] = __builtin_amdgcn_mfma_f32_16x16x32_bf16(af[mi], bfr[ni], acc[mi][ni], 0, 0, 0);
    __syncthreads();
  }

  const float* bias = (g == 0) ? bq : (g == 1) ? bk : bv;
  const float scale = (g == 0) ? 0.125f / inv_scale[0] : 1.0f;
#pragma unroll
  for (int ni = 0; ni < 4; ni++) {
    int col = n0 + wc * 64 + ni * 16 + lq;
    float bb = bias[col];
    int h = col >> 6, dh = col & 63;
#pragma unroll
    for (int mi = 0; mi < 4; mi++) {
#pragma unroll
      for (int r = 0; r < 4; r++) {
        int row = m0 + wr * 64 + mi * 16 + lg * 4 + r;
        int b = row >> 11, s2 = row & 2047;
        unsigned short bv16 = f2bf((acc[mi][ni][r] + bb) * scale);
        if (g == 0)
          Qh[(size_t)(b * 16 + h) * 131072 + (size_t)s2 * 64 + dh] = bv16;
        else if (g == 1)
          Kh[(size_t)(b * 16 + h) * 131072 + (size_t)s2 * 64 + dh] = bv16;
        else
          VhT[(size_t)((b * 16 + h) * 64 + dh) * 2048 + s2] = bv16;
      }
    }
  }
}

// ---------------------------------------------------------------------------
// Kernel 3: flash attention. grid (32 qtiles, 32 bh), 256 threads = 4 waves.
// Wave w owns 16 q-rows. Swapped QK^T (lane&15 = q), O^T PV orientation.
// K/Vt tiles staged via global_load_lds with source-side XOR chunk swizzle.
// ---------------------------------------------------------------------------
__global__ __launch_bounds__(256) void k_attn(
    const unsigned short* __restrict__ Qh, const unsigned short* __restrict__ Kh,
    const unsigned short* __restrict__ VhT, float* __restrict__ out) {
  __shared__ __align__(16) unsigned short Kt[64 * 64];
  __shared__ __align__(16) unsigned short Vt[64 * 64];
  __shared__ __align__(16) unsigned short Pl[4][16][72];  // per-wave P, +8 pad
  const int bh = blockIdx.y;  // b*16 + h
  const int qt = blockIdx.x;
  const int tid = threadIdx.x;
  const int w = tid >> 6, lane = tid & 63;
  const int lq = lane & 15, lg = lane >> 4;
  const int qrow = qt * 64 + w * 16 + lq;

  const unsigned short* qptr = Qh + ((size_t)bh * 2048 + qrow) * 64;
  bf16x8 qf0 = *(const bf16x8*)(qptr + lg * 8);
  bf16x8 qf1 = *(const bf16x8*)(qptr + 32 + lg * 8);

  f32x4 ofr[4];
#pragma unroll
  for (int dt = 0; dt < 4; dt++) ofr[dt] = (f32x4){0.f, 0.f, 0.f, 0.f};
  float m = -INFINITY, l = 0.f;

  for (int kv = 0; kv < 32; ++kv) {
    const int k0 = kv * 64;
#pragma unroll
    for (int p = 0; p < 2; ++p) {
      int i = (w * 2 + p) * 64 + lane;  // 0..511, 8 chunks per 64-elem row
      int row = i >> 3, c = i & 7;
      int cs = c ^ (row & 7);           // swizzle on the global source side
      gload_lds16(Kh + ((size_t)bh * 2048 + k0 + row) * 64 + cs * 8, (char*)Kt + i * 16);
      gload_lds16(VhT + ((size_t)bh * 64 + row) * 2048 + k0 + cs * 8, (char*)Vt + i * 16);
    }
    __syncthreads();

    // S^T = K . Q^T : sf[t4] holds S[k = t4*16 + lg*4 + r][q = lq]
    f32x4 sf[4];
#pragma unroll
    for (int t4 = 0; t4 < 4; t4++) {
      int row = t4 * 16 + lq;
      int c0 = lg ^ (row & 7), c1 = (4 + lg) ^ (row & 7);
      bf16x8 ka = *(const bf16x8*)((const char*)Kt + row * 128 + c0 * 16);
      bf16x8 kb = *(const bf16x8*)((const char*)Kt + row * 128 + c1 * 16);
      f32x4 z = (f32x4){0.f, 0.f, 0.f, 0.f};
      z = __builtin_amdgcn_mfma_f32_16x16x32_bf16(ka, qf0, z, 0, 0, 0);
      z = __builtin_amdgcn_mfma_f32_16x16x32_bf16(kb, qf1, z, 0, 0, 0);
      sf[t4] = z;
    }

    // online softmax (per lane: q = lq; 16 score values)
    float tmax = -INFINITY;
#pragma unroll
    for (int t4 = 0; t4 < 4; t4++)
#pragma unroll
      for (int r = 0; r < 4; r++) tmax = fmaxf(tmax, sf[t4][r]);
    tmax = fmaxf(tmax, __shfl_xor(tmax, 16));
    tmax = fmaxf(tmax, __shfl_xor(tmax, 32));
    float mnew = fmaxf(m, tmax);
    float corr = __expf(m - mnew);
    float psum = 0.f;
#pragma unroll
    for (int t4 = 0; t4 < 4; t4++) {
      float p0 = __expf(sf[t4][0] - mnew);
      float p1 = __expf(sf[t4][1] - mnew);
      float p2 = __expf(sf[t4][2] - mnew);
      float p3 = __expf(sf[t4][3] - mnew);
      psum += (p0 + p1) + (p2 + p3);
      uint32_t w0 = (uint32_t)f2bf(p0) | ((uint32_t)f2bf(p1) << 16);
      uint32_t w1 = (uint32_t)f2bf(p2) | ((uint32_t)f2bf(p3) << 16);
      *(uint2*)((char*)&Pl[w][lq][0] + (t4 * 16 + lg * 4) * 2) = make_uint2(w0, w1);
    }
    psum += __shfl_xor(psum, 16);
    psum += __shfl_xor(psum, 32);
    l = l * corr + psum;
    m = mnew;
#pragma unroll
    for (int dt = 0; dt < 4; dt++) ofr[dt] *= corr;

    // PV: O^T += Vt . P^T
    bf16x8 pf0 = *(const bf16x8*)((const char*)&Pl[w][lq][0] + lg * 16);
    bf16x8 pf1 = *(const bf16x8*)((const char*)&Pl[w][lq][0] + 64 + lg * 16);
#pragma unroll
    for (int dt = 0; dt < 4; dt++) {
      int row = dt * 16 + lq;
      int c0 = lg ^ (row & 7), c1 = (4 + lg) ^ (row & 7);
      bf16x8 va = *(const bf16x8*)((const char*)Vt + row * 128 + c0 * 16);
      bf16x8 vb = *(const bf16x8*)((const char*)Vt + row * 128 + c1 * 16);
      ofr[dt] = __builtin_amdgcn_mfma_f32_16x16x32_bf16(va, pf0, ofr[dt], 0, 0, 0);
      ofr[dt] = __builtin_amdgcn_mfma_f32_16x16x32_bf16(vb, pf1, ofr[dt], 0, 0, 0);
    }
    __syncthreads();
  }

  // out[b, s2, dh, h] = O[q=s2][dh] / l   (lane holds O^T[d][q=lq])
  float rl = 1.0f / l;
  int b = bh >> 4, h = bh & 15;
#pragma unroll
  for (int dt = 0; dt < 4; dt++)
#pragma unroll
    for (int r = 0; r < 4; r++) {
      int d = dt * 16 + lg * 4 + r;
      out[((size_t)b * 131072 + (size_t)qrow * 64 + d) * 16 + h] = ofr[dt][r] * rl;
    }
}

// ---------------------------------------------------------------------------
extern "C" void kernel_launch(void* const* d_in, const int* in_sizes, int n_in,
                              void* d_out, int out_size, void* d_ws, size_t ws_size,
                              hipStream_t stream) {
  const float* q   = (const float*)d_in[0];
  const float* k   = (const float*)d_in[1];
  const float* v   = (const float*)d_in[2];
  // d_in[3] = mask (unused by the reference forward)
  const float* inv = (const float*)d_in[4];
  const float* Wq  = (const float*)d_in[5];
  const float* bq  = (const float*)d_in[6];
  const float* Wk  = (const float*)d_in[7];
  const float* bk  = (const float*)d_in[8];
  const float* Wv  = (const float*)d_in[9];
  const float* bv  = (const float*)d_in[10];

  char* ws = (char*)d_ws;
  unsigned short* Xb  = (unsigned short*)(ws);              // 25,165,824 B
  unsigned short* Wb  = (unsigned short*)(ws + 25165824);   //  6,291,456 B
  unsigned short* Qh  = (unsigned short*)(ws + 31457280);   //  8,388,608 B
  unsigned short* Kh  = (unsigned short*)(ws + 39845888);   //  8,388,608 B
  unsigned short* VhT = (unsigned short*)(ws + 48234496);   //  8,388,608 B

  k_convert<<<15360, 256, 0, stream>>>(q, k, v, Wq, Wk, Wv, Xb, Wb);
  k_proj<<<dim3(256, 3), 256, 0, stream>>>(Xb, Wb, bq, bk, bv, inv, Qh, Kh, VhT);
  k_attn<<<dim3(32, 32), 256, 0, stream>>>(Qh, Kh, VhT, (float*)d_out);
}